// Round 6
// baseline (121.223 us; speedup 1.0000x reference)
//
#include <hip/hip_runtime.h>
#include <hip/hip_bf16.h>
#include <math.h>

typedef short bf16x8 __attribute__((ext_vector_type(8)));
typedef float f32x4  __attribute__((ext_vector_type(4)));

constexpr int H    = 256;
constexpr int KNB  = 32;
constexpr int TPB  = 512;
constexpr int G    = 4;      // supernodes per block
constexpr int CAP  = 1024;   // survivor cap per supernode (expected ~200)

__device__ __forceinline__ ushort f2bf(float x) {
    unsigned u = __float_as_uint(x);
    u += 0x7FFF + ((u >> 16) & 1);
    return (ushort)(u >> 16);
}

__device__ __forceinline__ float gelu_fast(float x) {
    float u = 0.7978845608028654f * (x + 0.044715f * x * x * x);
    float t = exp2f(-2.885390081777927f * u);
    return x / (1.0f + t);
}

// ---- prep: W1t[j][i] = bf16(W1[i][j]); pos4 = (x,y,z,|p|^2) ----
__global__ __launch_bounds__(256)
void prep(const float* __restrict__ W1, const float* __restrict__ pos, int N,
          ushort* __restrict__ W1t, float4* __restrict__ pos4) {
    const int b = blockIdx.x;
    if (b < 64) {
        __shared__ float tile[32][33];
        const int ti = b >> 3, tj = b & 7;
        const int r  = threadIdx.x >> 5, c = threadIdx.x & 31;
#pragma unroll
        for (int rr = r; rr < 32; rr += 8)
            tile[rr][c] = W1[(ti * 32 + rr) * H + tj * 32 + c];
        __syncthreads();
#pragma unroll
        for (int rr = r; rr < 32; rr += 8) {
            int j = tj * 32 + rr;
            W1t[j * H + ti * 32 + c] = f2bf(tile[c][rr]);
        }
    } else {
        int i = (b - 64) * 256 + threadIdx.x;
        if (i < N) {
            float x = pos[3 * i], y = pos[3 * i + 1], z = pos[3 * i + 2];
            pos4[i] = make_float4(x, y, z, fmaf(x, x, fmaf(y, y, z * z)));
        }
    }
}

// ---- kernel A: select + embed + GEMM1 for G supernodes; writes supE, hb ----
__global__ __launch_bounds__(TPB, 2)
void supernode_select(const float4* __restrict__ pos4, int N, int S,
                      const int* __restrict__ supidx,
                      const ushort* __restrict__ W1t, const float* __restrict__ b1,
                      float* __restrict__ featsM,   // [S][512]; cols 0..255 = supE
                      float* __restrict__ hbM)      // [S][256]
{
    // shared 16 KB region, time-multiplexed:
    //  sample: qmins f32[G][512] (8K) + pairmin f32[G][256] (4K)
    //  per-g:  qbuf u64[CAP] (8K)  then  msg bf16[32][256] (16K, XOR-swizzled)
    __shared__ __align__(16) char pool[16384];
    float* qmins   = (float*)pool;
    float* pairmin = (float*)(pool + 8192);
    unsigned long long* qbuf = (unsigned long long*)pool;
    ushort* msg    = (ushort*)pool;

    __shared__ int   idxbuf[G][CAP];    // 16 KB, persists across per-g loop
    __shared__ float rf[KNB][5];
    __shared__ int   sel[KNB];
    __shared__ float tauS[G];
    __shared__ int   cnt[G];

    const int s0   = blockIdx.x * G;
    const int t    = threadIdx.x;
    const int lane = t & 63;
    const int w    = t >> 6;

    constexpr float L2_10000 = 13.287712379549449f;

    // supernode positions (all G) in registers
    float sxg[G], syg[G], szg[G], c0g[G], c1g[G], c2g[G];
#pragma unroll
    for (int g = 0; g < G; g++) {
        int sg = s0 + g;
        int sidx = supidx[sg < S ? sg : 0];
        float4 sp = pos4[sidx];
        sxg[g] = sp.x; syg[g] = sp.y; szg[g] = sp.z;
        c0g[g] = -2.f * sp.x; c1g[g] = -2.f * sp.y; c2g[g] = -2.f * sp.z;
    }

    // hoist W1t fragments for this block's waves (reused for all G GEMM1s)
    const int lr = lane & 15;
    const int lg = lane >> 4;
    bf16x8 aA[8][2];
#pragma unroll
    for (int kk = 0; kk < 8; kk++) {
        const int i0 = kk * 32 + lg * 8;
        aA[kk][0] = *(const bf16x8*)(W1t + ((32 * w      + lr) << 8) + i0);
        aA[kk][1] = *(const bf16x8*)(W1t + ((32 * w + 16 + lr) << 8) + i0);
    }

    // ---- phase 0: supernode abs-pos embeds -> featsM[sg][0..255] ----
    if (t < H) {
#pragma unroll
        for (int g = 0; g < G; g++) {
            if (s0 + g >= S) break;
            float se = 0.f;
            if (t < 252) {
                int c  = t / 84;
                int rr = t - c * 84;
                int f  = (rr < 42) ? rr : rr - 42;
                float coord = (c == 0) ? sxg[g] : ((c == 1) ? syg[g] : szg[g]);
                float ang = coord * exp2f(-(float)f * (L2_10000 / 42.f));
                se = (rr < 42) ? __sinf(ang) : __cosf(ang);
            }
            featsM[(s0 + g) * (2 * H) + t] = se;
        }
    }

    // ---- phase 1: sample 8192 pts, per-thread min q_g = |p|^2 - 2 s_g.p ----
    {
        float mn[G];
#pragma unroll
        for (int g = 0; g < G; g++) mn[g] = INFINITY;
#pragma unroll
        for (int n = 0; n < 4; n++) {
            int i = n * 2048 + 4 * t;
            if (i + 3 < N) {
#pragma unroll
                for (int u = 0; u < 4; u++) {
                    float4 P = pos4[i + u];
#pragma unroll
                    for (int g = 0; g < G; g++) {
                        float q = fmaf(P.x, c0g[g], fmaf(P.y, c1g[g], fmaf(P.z, c2g[g], P.w)));
                        mn[g] = fminf(mn[g], q);
                    }
                }
            }
        }
#pragma unroll
        for (int g = 0; g < G; g++) qmins[g * 512 + t] = mn[g];
    }
    if (t < G) cnt[t] = 0;
    __syncthreads();
    if (t < 256) {
#pragma unroll
        for (int g = 0; g < G; g++)
            pairmin[g * 256 + t] = fminf(qmins[g * 512 + 2 * t], qmins[g * 512 + 2 * t + 1]);
    }
    __syncthreads();
    // rank-select 32nd-smallest pair-min per g (disjoint 32-pt groups => >=32 pts <= tau)
    if (t < 256) {
#pragma unroll
        for (int g = 0; g < G; g++) {
            float my = pairmin[g * 256 + t];
            int lt = 0, le = 0;
            for (int u = 0; u < 256; u += 4) {
                float4 v = *(const float4*)&pairmin[g * 256 + u];
                lt += (v.x < my) + (v.y < my) + (v.z < my) + (v.w < my);
                le += (v.x <= my) + (v.y <= my) + (v.z <= my) + (v.w <= my);
            }
            if (lt <= 31 && le > 31) tauS[g] = my;
        }
    }
    __syncthreads();
    float tau[G];
#pragma unroll
    for (int g = 0; g < G; g++)
        tau[g] = (s0 + g < S) ? tauS[g] + 1e-3f : -INFINITY;
    __syncthreads();

    // ---- phase 2: filter all N points into G survivor lists ----
    {
        auto flt = [&](float4 P, int i) {
#pragma unroll
            for (int g = 0; g < G; g++) {
                float q = fmaf(P.x, c0g[g], fmaf(P.y, c1g[g], fmaf(P.z, c2g[g], P.w)));
                if (q <= tau[g]) {
                    int sl = atomicAdd(&cnt[g], 1);
                    if (sl < CAP) idxbuf[g][sl] = i;
                }
            }
        };
        int base = 0;
        for (; base + 4 * TPB <= N; base += 4 * TPB) {
            int i = base + 4 * t;
            float4 P0 = pos4[i], P1 = pos4[i + 1], P2 = pos4[i + 2], P3 = pos4[i + 3];
            flt(P0, i); flt(P1, i + 1); flt(P2, i + 2); flt(P3, i + 3);
        }
        for (int i = base + t; i < N; i += TPB) flt(pos4[i], i);
    }
    __syncthreads();

    // ---- per-supernode: exact top-32, embed, MFMA GEMM1 ----
    for (int g = 0; g < G; g++) {
        const int sg = s0 + g;
        if (sg >= S) break;
        const float sx = sxg[g], sy = syg[g], sz = szg[g];
        const int M = min(cnt[g], CAP);
        const int Mpad = (M + 1) & ~1;

        // exact d2, pack (d2,idx) u64
        for (int u = t; u < Mpad; u += TPB) {
            unsigned long long pk = ~0ull;
            if (u < M) {
                int idx = idxbuf[g][u];
                float4 P = pos4[idx];
                float dx = sx - P.x, dy = sy - P.y, dz = sz - P.z;
                float d2 = dx * dx + dy * dy + dz * dz;
                pk = ((unsigned long long)__float_as_uint(d2) << 32) | (unsigned)idx;
            }
            qbuf[u] = pk;
        }
        __syncthreads();
        for (int u = t; u < M; u += TPB) {
            unsigned long long mine = qbuf[u];
            int rank = 0;
            for (int v = 0; v < Mpad; v += 2) {
                unsigned long long a = qbuf[v], b = qbuf[v + 1];
                rank += (a < mine) + (b < mine);
            }
            if (rank < KNB) sel[rank] = (int)(mine & 0xffffffffu);
        }
        __syncthreads();

        if (t < KNB) {
            int ni = sel[t];
            float4 P = pos4[ni];
            float rx = sx - P.x, ry = sy - P.y, rz = sz - P.z;
            float dd = sqrtf(rx * rx + ry * ry + rz * rz);
            rf[t][0] = rx; rf[t][1] = ry; rf[t][2] = rz; rf[t][3] = dd;
        }
        __syncthreads();

        // sincos embed -> msg[k][i] bf16, row-XOR swizzle (overwrites qbuf)
#pragma unroll
        for (int n = 0; n < 8; n++) {
            int item = t + n * TPB;
            int f = item & 31;
            int c = (item >> 5) & 3;
            int k = item >> 7;
            float ang = rf[k][c] * exp2f(-(float)f * (L2_10000 / 32.f));
            int swz = (k & 7) << 3;
            msg[((k << 8) | (c * 64 + f))      ^ swz] = f2bf(__sinf(ang));
            msg[((k << 8) | (c * 64 + 32 + f)) ^ swz] = f2bf(__cosf(ang));
        }
        __syncthreads();

        // MFMA GEMM1: h[j][k] = sum_i W1t[j][i]*msg[k][i]; gelu; mean_k -> hbM
        {
            f32x4 acc00 = {0,0,0,0}, acc01 = {0,0,0,0};
            f32x4 acc10 = {0,0,0,0}, acc11 = {0,0,0,0};
#pragma unroll
            for (int kk = 0; kk < 8; kk++) {
                const int i0 = kk * 32 + lg * 8;
                const int swz = (lr & 7) << 3;
                bf16x8 b0 = *(const bf16x8*)(msg + ((( lr       << 8) | i0) ^ swz));
                bf16x8 b1 = *(const bf16x8*)(msg + ((((lr + 16) << 8) | i0) ^ swz));
                acc00 = __builtin_amdgcn_mfma_f32_16x16x32_bf16(aA[kk][0], b0, acc00, 0, 0, 0);
                acc01 = __builtin_amdgcn_mfma_f32_16x16x32_bf16(aA[kk][0], b1, acc01, 0, 0, 0);
                acc10 = __builtin_amdgcn_mfma_f32_16x16x32_bf16(aA[kk][1], b0, acc10, 0, 0, 0);
                acc11 = __builtin_amdgcn_mfma_f32_16x16x32_bf16(aA[kk][1], b1, acc11, 0, 0, 0);
            }
            float part[8];
#pragma unroll
            for (int m = 0; m < 2; m++)
#pragma unroll
                for (int r = 0; r < 4; r++) {
                    int j = 32 * w + 16 * m + 4 * lg + r;
                    float bj = b1[j];
                    float h0 = (m == 0 ? acc00[r] : acc10[r]) + bj;
                    float h1 = (m == 0 ? acc01[r] : acc11[r]) + bj;
                    part[m * 4 + r] = gelu_fast(h0) + gelu_fast(h1);
                }
#pragma unroll
            for (int off = 1; off < 16; off <<= 1)
#pragma unroll
                for (int u = 0; u < 8; u++)
                    part[u] += __shfl_xor(part[u], off);
            if (lr == 0) {
#pragma unroll
                for (int u = 0; u < 8; u++) {
                    int m = u >> 2, r = u & 3;
                    hbM[sg * H + 32 * w + 16 * m + 4 * lg + r] = part[u] * (1.0f / 32.0f);
                }
            }
        }
        __syncthreads();   // pool free for next g
    }
}

// ---- kernel B: C[M x N] = A[M x K] @ B[K x N] + bias, fp32 tiled 32x32 ----
__global__ __launch_bounds__(256)
void gemm_bias(const float* __restrict__ A, const float* __restrict__ B,
               const float* __restrict__ bias, float* __restrict__ C,
               int K, int N, int ldc)
{
    __shared__ float As[32][36];
    __shared__ float Bs[32][36];
    const int t  = threadIdx.x;
    const int bm = blockIdx.x, bn = blockIdx.y;
    const int tx = t & 15, ty = t >> 4;
    const int lr = t >> 3, lc = (t & 7) * 4;   // loader row / col

    float acc[2][2] = {{0.f, 0.f}, {0.f, 0.f}};

    for (int kk = 0; kk < K; kk += 32) {
        float4 av = *(const float4*)&A[(bm * 32 + lr) * K + kk + lc];
        float4 bv = *(const float4*)&B[(kk + lr) * N + bn * 32 + lc];
        *(float4*)&As[lr][lc] = av;
        *(float4*)&Bs[lr][lc] = bv;
        __syncthreads();
#pragma unroll
        for (int k = 0; k < 32; k++) {
            float a0 = As[2 * ty][k], a1 = As[2 * ty + 1][k];
            float2 b01 = *(const float2*)&Bs[k][2 * tx];
            acc[0][0] += a0 * b01.x; acc[0][1] += a0 * b01.y;
            acc[1][0] += a1 * b01.x; acc[1][1] += a1 * b01.y;
        }
        __syncthreads();
    }
#pragma unroll
    for (int u = 0; u < 2; u++) {
        int row = bm * 32 + 2 * ty + u;
        int col = bn * 32 + 2 * tx;
        C[row * ldc + col]     = acc[u][0] + bias[col];
        C[row * ldc + col + 1] = acc[u][1] + bias[col + 1];
    }
}

extern "C" void kernel_launch(void* const* d_in, const int* in_sizes, int n_in,
                              void* d_out, int out_size, void* d_ws, size_t ws_size,
                              hipStream_t stream) {
    const float* pos = (const float*)d_in[0];
    const int*   sup = (const int*)d_in[1];
    const float* W1  = (const float*)d_in[2];
    const float* b1  = (const float*)d_in[3];
    const float* W2  = (const float*)d_in[4];
    const float* b2  = (const float*)d_in[5];
    const float* Wp  = (const float*)d_in[6];
    const float* bp  = (const float*)d_in[7];

    const int N = in_sizes[0] / 3;
    const int S = in_sizes[1];
    float* out = (float*)d_out;

    char* ws = (char*)d_ws;
    ushort* W1t    = (ushort*)ws;                         // 128 KB
    float4* pos4   = (float4*)(ws + (128 << 10));         // 800 KB
    float*  hbM    = (float*)(ws + (1024 << 10));         // S*256*4 = 1 MB
    float*  featsM = (float*)(ws + (2048 << 10));         // S*512*4 = 2 MB

    prep<<<64 + (N + 255) / 256, 256, 0, stream>>>(W1, pos, N, W1t, pos4);
    supernode_select<<<(S + G - 1) / G, TPB, 0, stream>>>(pos4, N, S, sup, W1t, b1,
                                                          featsM, hbM);
    // B1: agg = hbM @ W2 + b2  -> featsM[:, 256:512]
    gemm_bias<<<dim3(S / 32, H / 32), 256, 0, stream>>>(hbM, W2, b2, featsM + H,
                                                        H, H, 2 * H);
    // B2: out = featsM @ Wp + bp
    gemm_bias<<<dim3(S / 32, H / 32), 256, 0, stream>>>(featsM, Wp, bp, out,
                                                        2 * H, H, H);
}

// Round 7
// 109.410 us; speedup vs baseline: 1.1080x; 1.1080x over previous
//
#include <hip/hip_runtime.h>
#include <hip/hip_bf16.h>
#include <math.h>

typedef short bf16x8 __attribute__((ext_vector_type(8)));
typedef float f32x4  __attribute__((ext_vector_type(4)));

constexpr int H    = 256;
constexpr int KNB  = 32;
constexpr int CAP  = 1024;   // survivor cap per supernode (expected ~280)
constexpr int G    = 2;      // supernodes per select-block

__device__ __forceinline__ ushort f2bf(float x) {
    unsigned u = __float_as_uint(x);
    u += 0x7FFF + ((u >> 16) & 1);
    return (ushort)(u >> 16);
}

__device__ __forceinline__ float gelu_fast(float x) {
    float u = 0.7978845608028654f * (x + 0.044715f * x * x * x);
    float t = exp2f(-2.885390081777927f * u);
    return x / (1.0f + t);
}

// ---- prep: W1t[j][i] = bf16(W1[i][j]); pos4 = (x,y,z,|p|^2) ----
__global__ __launch_bounds__(256)
void prep(const float* __restrict__ W1, const float* __restrict__ pos, int N,
          ushort* __restrict__ W1t, float4* __restrict__ pos4) {
    const int b = blockIdx.x;
    if (b < 64) {
        __shared__ float tile[32][33];
        const int ti = b >> 3, tj = b & 7;
        const int r  = threadIdx.x >> 5, c = threadIdx.x & 31;
#pragma unroll
        for (int rr = r; rr < 32; rr += 8)
            tile[rr][c] = W1[(ti * 32 + rr) * H + tj * 32 + c];
        __syncthreads();
#pragma unroll
        for (int rr = r; rr < 32; rr += 8) {
            int j = tj * 32 + rr;
            W1t[j * H + ti * 32 + c] = f2bf(tile[c][rr]);
        }
    } else {
        int i = (b - 64) * 256 + threadIdx.x;
        if (i < N) {
            float x = pos[3 * i], y = pos[3 * i + 1], z = pos[3 * i + 2];
            pos4[i] = make_float4(x, y, z, fmaf(x, x, fmaf(y, y, z * z)));
        }
    }
}

// ---- K2: exact kNN select for G supernodes; writes supE + rel features ----
__global__ __launch_bounds__(512, 8)
void knn_select(const float4* __restrict__ pos4, int N, int S,
                const int* __restrict__ supidx,
                float* __restrict__ featsM,    // [S][512]; cols 0..255 = supE
                float4* __restrict__ rfM)      // [S][32] = (rx,ry,rz,d)
{
    __shared__ float poolA[G * 512];    // qmins[g][512]; reused as d2buf[1024]
    __shared__ float pairmin[G * 256];
    __shared__ int   idxbuf[G][CAP];
    __shared__ int   sel[KNB];
    __shared__ float tauS[G];
    __shared__ int   cnt[G];

    const int s0 = blockIdx.x * G;
    const int t  = threadIdx.x;

    constexpr float L2_10000 = 13.287712379549449f;

    float sxg[G], syg[G], szg[G], c0g[G], c1g[G], c2g[G];
#pragma unroll
    for (int g = 0; g < G; g++) {
        int sg = s0 + g;
        int sidx = supidx[sg < S ? sg : 0];
        float4 sp = pos4[sidx];
        sxg[g] = sp.x; syg[g] = sp.y; szg[g] = sp.z;
        c0g[g] = -2.f * sp.x; c1g[g] = -2.f * sp.y; c2g[g] = -2.f * sp.z;
    }

    // supernode abs-pos embed -> featsM[sg][0..255]
    if (t < 256) {
#pragma unroll
        for (int g = 0; g < G; g++) {
            if (s0 + g >= S) break;
            float se = 0.f;
            if (t < 252) {
                int c  = t / 84;
                int rr = t - c * 84;
                int f  = (rr < 42) ? rr : rr - 42;
                float coord = (c == 0) ? sxg[g] : ((c == 1) ? syg[g] : szg[g]);
                float ang = coord * exp2f(-(float)f * (L2_10000 / 42.f));
                se = (rr < 42) ? __sinf(ang) : __cosf(ang);
            }
            featsM[(s0 + g) * (2 * H) + t] = se;
        }
    }

    // sample 8192 points -> per-thread min of q = |p|^2 - 2 s.p
    {
        float mn[G];
#pragma unroll
        for (int g = 0; g < G; g++) mn[g] = INFINITY;
#pragma unroll
        for (int n = 0; n < 4; n++) {
            int i = n * 2048 + 4 * t;
            if (i + 3 < N) {
#pragma unroll
                for (int u = 0; u < 4; u++) {
                    float4 P = pos4[i + u];
#pragma unroll
                    for (int g = 0; g < G; g++) {
                        float q = fmaf(P.x, c0g[g], fmaf(P.y, c1g[g], fmaf(P.z, c2g[g], P.w)));
                        mn[g] = fminf(mn[g], q);
                    }
                }
            }
        }
#pragma unroll
        for (int g = 0; g < G; g++) poolA[g * 512 + t] = mn[g];
    }
    if (t < G) cnt[t] = 0;
    __syncthreads();
    if (t < 256) {
#pragma unroll
        for (int g = 0; g < G; g++)
            pairmin[g * 256 + t] = fminf(poolA[g * 512 + 2 * t], poolA[g * 512 + 2 * t + 1]);
    }
    __syncthreads();
    // 32nd-smallest of 256 disjoint-group minima => >=32 points have q <= tau
    if (t < 256) {
#pragma unroll
        for (int g = 0; g < G; g++) {
            float my = pairmin[g * 256 + t];
            int lt = 0, le = 0;
            for (int u = 0; u < 256; u += 4) {
                float4 v = *(const float4*)&pairmin[g * 256 + u];
                lt += (v.x < my) + (v.y < my) + (v.z < my) + (v.w < my);
                le += (v.x <= my) + (v.y <= my) + (v.z <= my) + (v.w <= my);
            }
            if (lt <= 31 && le > 31) tauS[g] = my;
        }
    }
    __syncthreads();
    float tau[G];
#pragma unroll
    for (int g = 0; g < G; g++)
        tau[g] = (s0 + g < S) ? tauS[g] + 1e-3f : -INFINITY;
    __syncthreads();   // poolA free for reuse after this point

    // filter all N points into G survivor lists
    {
        auto flt = [&](float4 P, int i) {
#pragma unroll
            for (int g = 0; g < G; g++) {
                float q = fmaf(P.x, c0g[g], fmaf(P.y, c1g[g], fmaf(P.z, c2g[g], P.w)));
                if (q <= tau[g]) {
                    int sl = atomicAdd(&cnt[g], 1);
                    if (sl < CAP) idxbuf[g][sl] = i;
                }
            }
        };
        int base = 0;
        for (; base + 4 * 512 <= N; base += 4 * 512) {
            int i = base + 4 * t;
            float4 P0 = pos4[i], P1 = pos4[i + 1], P2 = pos4[i + 2], P3 = pos4[i + 3];
            flt(P0, i); flt(P1, i + 1); flt(P2, i + 2); flt(P3, i + 3);
        }
        for (int i = base + t; i < N; i += 512) flt(pos4[i], i);
    }
    __syncthreads();

    // per-supernode: exact d2, rank-merge -> top-32, rel features
    for (int g = 0; g < G; g++) {
        const int sg = s0 + g;
        if (sg >= S) break;
        const float sx = sxg[g], sy = syg[g], sz = szg[g];
        const int M = min(cnt[g], CAP);
        const int Mpad = (M + 3) & ~3;

        for (int u = t; u < Mpad; u += 512) {
            float d2 = INFINITY;
            if (u < M) {
                int idx = idxbuf[g][u];
                float4 P = pos4[idx];
                float dx = sx - P.x, dy = sy - P.y, dz = sz - P.z;
                d2 = dx * dx + dy * dy + dz * dz;
            } else {
                idxbuf[g][u] = 0x7fffffff;
            }
            poolA[u] = d2;
        }
        __syncthreads();
        for (int u = t; u < M; u += 512) {
            float my  = poolA[u];
            int   myi = idxbuf[g][u];
            int rank = 0;
            for (int v = 0; v < Mpad; v += 4) {
                float4 dv = *(const float4*)&poolA[v];
                int4   iv = *(const int4*)&idxbuf[g][v];
                rank += (dv.x < my) || (dv.x == my && iv.x < myi);
                rank += (dv.y < my) || (dv.y == my && iv.y < myi);
                rank += (dv.z < my) || (dv.z == my && iv.z < myi);
                rank += (dv.w < my) || (dv.w == my && iv.w < myi);
            }
            if (rank < KNB) sel[rank] = myi;
        }
        __syncthreads();
        if (t < KNB) {
            int ni = sel[t];
            float4 P = pos4[ni];
            float rx = sx - P.x, ry = sy - P.y, rz = sz - P.z;
            float dd = sqrtf(rx * rx + ry * ry + rz * rz);
            rfM[sg * KNB + t] = make_float4(rx, ry, rz, dd);
        }
        __syncthreads();   // protect sel + poolA before next g
    }
}

// ---- K3: sincos embed + MFMA GEMM1 + gelu + mean_k -> hbM ----
__global__ __launch_bounds__(512, 4)
void embed_gemm1(const float4* __restrict__ rfM,
                 const ushort* __restrict__ W1t, const float* __restrict__ b1,
                 float* __restrict__ hbM)
{
    __shared__ ushort msg[KNB * H];   // 16 KB bf16 msg[k][i], XOR-swizzled rows
    __shared__ float  rf[KNB][5];

    const int s    = blockIdx.x;
    const int t    = threadIdx.x;
    const int lane = t & 63;
    const int w    = t >> 6;

    constexpr float L2_10000 = 13.287712379549449f;

    if (t < KNB) {
        float4 v = rfM[s * KNB + t];
        rf[t][0] = v.x; rf[t][1] = v.y; rf[t][2] = v.z; rf[t][3] = v.w;
    }
    __syncthreads();

#pragma unroll
    for (int n = 0; n < 8; n++) {
        int item = t + n * 512;
        int f = item & 31;
        int c = (item >> 5) & 3;
        int k = item >> 7;
        float ang = rf[k][c] * exp2f(-(float)f * (L2_10000 / 32.f));
        int swz = (k & 7) << 3;
        msg[((k << 8) | (c * 64 + f))      ^ swz] = f2bf(__sinf(ang));
        msg[((k << 8) | (c * 64 + 32 + f)) ^ swz] = f2bf(__cosf(ang));
    }
    __syncthreads();

    {
        const int lr = lane & 15;
        const int lg = lane >> 4;
        f32x4 acc00 = {0,0,0,0}, acc01 = {0,0,0,0};
        f32x4 acc10 = {0,0,0,0}, acc11 = {0,0,0,0};
#pragma unroll
        for (int kk = 0; kk < 8; kk++) {
            const int i0 = kk * 32 + lg * 8;
            bf16x8 a0 = *(const bf16x8*)(W1t + ((32 * w      + lr) << 8) + i0);
            bf16x8 a1 = *(const bf16x8*)(W1t + ((32 * w + 16 + lr) << 8) + i0);
            const int swz = (lr & 7) << 3;
            bf16x8 b0 = *(const bf16x8*)(msg + ((( lr       << 8) | i0) ^ swz));
            bf16x8 b1v = *(const bf16x8*)(msg + ((((lr + 16) << 8) | i0) ^ swz));
            acc00 = __builtin_amdgcn_mfma_f32_16x16x32_bf16(a0, b0, acc00, 0, 0, 0);
            acc01 = __builtin_amdgcn_mfma_f32_16x16x32_bf16(a0, b1v, acc01, 0, 0, 0);
            acc10 = __builtin_amdgcn_mfma_f32_16x16x32_bf16(a1, b0, acc10, 0, 0, 0);
            acc11 = __builtin_amdgcn_mfma_f32_16x16x32_bf16(a1, b1v, acc11, 0, 0, 0);
        }
        float part[8];
#pragma unroll
        for (int m = 0; m < 2; m++)
#pragma unroll
            for (int r = 0; r < 4; r++) {
                int j = 32 * w + 16 * m + 4 * lg + r;
                float bj = b1[j];
                float h0 = (m == 0 ? acc00[r] : acc10[r]) + bj;
                float h1 = (m == 0 ? acc01[r] : acc11[r]) + bj;
                part[m * 4 + r] = gelu_fast(h0) + gelu_fast(h1);
            }
#pragma unroll
        for (int off = 1; off < 16; off <<= 1)
#pragma unroll
            for (int u = 0; u < 8; u++)
                part[u] += __shfl_xor(part[u], off);
        const int lr2 = lane & 15;
        if (lr2 == 0) {
#pragma unroll
            for (int u = 0; u < 8; u++) {
                int m = u >> 2, r = u & 3;
                hbM[s * H + 32 * w + 16 * m + 4 * (lane >> 4) + r] = part[u] * (1.0f / 32.0f);
            }
        }
    }
}

// ---- kernel B: C[M x N] = A[M x K] @ B[K x N] + bias, fp32 tiled 32x32 ----
__global__ __launch_bounds__(256)
void gemm_bias(const float* __restrict__ A, const float* __restrict__ B,
               const float* __restrict__ bias, float* __restrict__ C,
               int K, int N, int ldc)
{
    __shared__ float As[32][36];
    __shared__ float Bs[32][36];
    const int t  = threadIdx.x;
    const int bm = blockIdx.x, bn = blockIdx.y;
    const int tx = t & 15, ty = t >> 4;
    const int lr = t >> 3, lc = (t & 7) * 4;

    float acc[2][2] = {{0.f, 0.f}, {0.f, 0.f}};

    for (int kk = 0; kk < K; kk += 32) {
        float4 av = *(const float4*)&A[(bm * 32 + lr) * K + kk + lc];
        float4 bv = *(const float4*)&B[(kk + lr) * N + bn * 32 + lc];
        *(float4*)&As[lr][lc] = av;
        *(float4*)&Bs[lr][lc] = bv;
        __syncthreads();
#pragma unroll
        for (int k = 0; k < 32; k++) {
            float a0 = As[2 * ty][k], a1 = As[2 * ty + 1][k];
            float2 b01 = *(const float2*)&Bs[k][2 * tx];
            acc[0][0] += a0 * b01.x; acc[0][1] += a0 * b01.y;
            acc[1][0] += a1 * b01.x; acc[1][1] += a1 * b01.y;
        }
        __syncthreads();
    }
#pragma unroll
    for (int u = 0; u < 2; u++) {
        int row = bm * 32 + 2 * ty + u;
        int col = bn * 32 + 2 * tx;
        C[row * ldc + col]     = acc[u][0] + bias[col];
        C[row * ldc + col + 1] = acc[u][1] + bias[col + 1];
    }
}

extern "C" void kernel_launch(void* const* d_in, const int* in_sizes, int n_in,
                              void* d_out, int out_size, void* d_ws, size_t ws_size,
                              hipStream_t stream) {
    const float* pos = (const float*)d_in[0];
    const int*   sup = (const int*)d_in[1];
    const float* W1  = (const float*)d_in[2];
    const float* b1  = (const float*)d_in[3];
    const float* W2  = (const float*)d_in[4];
    const float* b2  = (const float*)d_in[5];
    const float* Wp  = (const float*)d_in[6];
    const float* bp  = (const float*)d_in[7];

    const int N = in_sizes[0] / 3;
    const int S = in_sizes[1];
    float* out = (float*)d_out;

    char* ws = (char*)d_ws;
    ushort* W1t    = (ushort*)ws;                         // 128 KB
    float4* pos4   = (float4*)(ws + (128 << 10));         // 800 KB
    float*  hbM    = (float*)(ws + (1024 << 10));         // 1 MB
    float*  featsM = (float*)(ws + (2048 << 10));         // 2 MB
    float4* rfM    = (float4*)(ws + (4096 << 10));        // 512 KB

    prep<<<64 + (N + 255) / 256, 256, 0, stream>>>(W1, pos, N, W1t, pos4);
    knn_select<<<(S + G - 1) / G, 512, 0, stream>>>(pos4, N, S, sup, featsM, rfM);
    embed_gemm1<<<S, 512, 0, stream>>>(rfM, W1t, b1, hbM);
    gemm_bias<<<dim3(S / 32, H / 32), 256, 0, stream>>>(hbM, W2, b2, featsM + H,
                                                        H, H, 2 * H);
    gemm_bias<<<dim3(S / 32, H / 32), 256, 0, stream>>>(featsM, Wp, bp, out,
                                                        2 * H, H, H);
}